// Round 14
// baseline (337.566 us; speedup 1.0000x reference)
//
#include <hip/hip_runtime.h>

typedef __bf16 bf16x8_t __attribute__((ext_vector_type(8)));
typedef float f32x4_t __attribute__((ext_vector_type(4)));

#define AS1 __attribute__((address_space(1)))
#define AS3 __attribute__((address_space(3)))

__device__ __forceinline__ unsigned short f2b(float f) {
    unsigned u = __builtin_bit_cast(unsigned, f);
    u += 0x7fffu + ((u >> 16) & 1u);
    return (unsigned short)(u >> 16);
}
__device__ __forceinline__ float b2f(unsigned short s) {
    return __builtin_bit_cast(float, (unsigned)s << 16);
}

// ---------------------------------------------------------------------------
// fp32 -> bf16 convert, 4 elems/thread
// ---------------------------------------------------------------------------
__global__ __launch_bounds__(256) void k_f2b(const float* __restrict__ in,
                                             unsigned short* __restrict__ out,
                                             int n4) {
    int i = blockIdx.x * 256 + threadIdx.x;
    if (i >= n4) return;
    float4 v = reinterpret_cast<const float4*>(in)[i];
    ushort4 o;
    o.x = f2b(v.x); o.y = f2b(v.y); o.z = f2b(v.z); o.w = f2b(v.w);
    reinterpret_cast<ushort4*>(out)[i] = o;
}

// ===========================================================================
// ENGINE A (measured qkv 85us, 0 conflicts): 256x128, BK=32, 512 thr, 8 waves
// (4Mx2N), wave 64x64. LDS 3x24KB -> 2 blocks/CU. Counted vmcnt(3) 3-buffer.
// 64B-row swizzle s(fr)=(fr>>1)&3. qkv_qk only.
// ===========================================================================
#define STAGE3(tt, bb) do {                                                    \
    char* dst_ = smem + (bb) * 24576;                                          \
    const size_t kof_ = (size_t)(tt) * 32;                                     \
    __builtin_amdgcn_global_load_lds((const AS1 void*)(pA0 + kof_),            \
        (AS3 void*)(dst_ + wave * 1024), 16, 0, 0);                            \
    __builtin_amdgcn_global_load_lds((const AS1 void*)(pA1 + kof_),            \
        (AS3 void*)(dst_ + 8192 + wave * 1024), 16, 0, 0);                     \
    __builtin_amdgcn_global_load_lds((const AS1 void*)(pB0 + kof_),            \
        (AS3 void*)(dst_ + 16384 + wave * 1024), 16, 0, 0);                    \
} while (0)

__device__ __forceinline__ void gemm_ml_128(
    const unsigned short* __restrict__ A, int lda,
    const unsigned short* __restrict__ B, int ldb,
    int K, char* smem, f32x4_t acc[4][4]) {
    const int tid = threadIdx.x;
    const int wave = tid >> 6, lane = tid & 63;
    const int wm = wave >> 1, wn = wave & 1;
    const int fr = lane & 15, g = lane >> 4;

    const int scolB = ((lane & 3) * 16) ^ (((lane >> 3) & 3) << 4);
    const unsigned short* pA0 = A + (size_t)(wave * 16 + (lane >> 2)) * lda + (scolB >> 1);
    const unsigned short* pA1 = pA0 + (size_t)128 * lda;
    const unsigned short* pB0 = B + (size_t)(wave * 16 + (lane >> 2)) * ldb + (scolB >> 1);

    const int rswz = (g * 16) ^ (((fr >> 1) & 3) << 4);
    int offA[4], offB[4];
#pragma unroll
    for (int mi = 0; mi < 4; ++mi)
        offA[mi] = (wm * 64 + mi * 16 + fr) * 64 + rswz;
#pragma unroll
    for (int ni = 0; ni < 4; ++ni)
        offB[ni] = 16384 + (wn * 64 + ni * 16 + fr) * 64 + rswz;

#pragma unroll
    for (int mi = 0; mi < 4; ++mi)
#pragma unroll
        for (int ni = 0; ni < 4; ++ni)
            acc[mi][ni] = (f32x4_t){0.f, 0.f, 0.f, 0.f};

    const int NT = K >> 5;

    STAGE3(0, 0);
    STAGE3(1, 1);

    int cb = 0;
    for (int t = 0; t < NT; ++t) {
        if (t + 1 < NT) asm volatile("s_waitcnt vmcnt(3)" ::: "memory");
        else            asm volatile("s_waitcnt vmcnt(0)" ::: "memory");
        asm volatile("s_barrier" ::: "memory");
        if (t + 2 < NT) {
            int sb = cb + 2; if (sb >= 3) sb -= 3;
            STAGE3(t + 2, sb);
        }
        const char* rb = smem + cb * 24576;
        bf16x8_t af[4], bfv[4];
#pragma unroll
        for (int mi = 0; mi < 4; ++mi)
            af[mi] = *reinterpret_cast<const bf16x8_t*>(rb + offA[mi]);
#pragma unroll
        for (int ni = 0; ni < 4; ++ni)
            bfv[ni] = *reinterpret_cast<const bf16x8_t*>(rb + offB[ni]);
        __builtin_amdgcn_s_setprio(1);
#pragma unroll
        for (int mi = 0; mi < 4; ++mi)
#pragma unroll
            for (int ni = 0; ni < 4; ++ni)
                acc[mi][ni] = __builtin_amdgcn_mfma_f32_16x16x32_bf16(
                    af[mi], bfv[ni], acc[mi][ni], 0, 0, 0);
        __builtin_amdgcn_s_setprio(0);
        cb = (cb + 1 == 3) ? 0 : cb + 1;
    }
}

#define E128_IDX                                                \
    const int lane = threadIdx.x & 63, wave = threadIdx.x >> 6; \
    const int e_r0 = (wave >> 1) * 64 + (lane >> 4) * 4;        \
    const int e_c0 = (wave & 1) * 64 + (lane & 15);

#define E128_LOOP(...)                                          \
    _Pragma("unroll") for (int mi = 0; mi < 4; ++mi)            \
    _Pragma("unroll") for (int ni = 0; ni < 4; ++ni)            \
    _Pragma("unroll") for (int j = 0; j < 4; ++j) { __VA_ARGS__ }

// ===========================================================================
// Shared 256x256 geometry helpers (Engines B and C): 512 thr, 8 waves at
// (wsm=(wave>>2)&1, wsn=wave&3); quadrant (qm,qn) at block offset
// (qm*128, qn*128); per-wave per-quadrant 64x32 = 4x2 frags.
// LDS buffer = 64KB: A halves [128][64]bf16 @ h*16384, B @ 32768+h*16384.
// 128B-row swizzle ((fr&7)<<4) both-sides; measured 0 conflicts.
// ===========================================================================
#define STA(h, i)                                                              \
    __builtin_amdgcn_global_load_lds(                                         \
        (const AS1 void*)(pA + kof + (size_t)((h) * 128 + (i) * 8) * lda),    \
        (AS3 void*)(wb + (h) * 16384 + wave * 2048 + (i) * 1024), 16, 0, 0)
#define STB(h, i)                                                              \
    __builtin_amdgcn_global_load_lds(                                         \
        (const AS1 void*)(pB + kof + (size_t)((h) * 128 + (i) * 8) * ldb),    \
        (AS3 void*)(wb + 32768 + (h) * 16384 + wave * 2048 + (i) * 1024), 16, 0, 0)

#define READ_A(qm)                                                             \
    _Pragma("unroll") for (int mi = 0; mi < 4; ++mi)                           \
        _Pragma("unroll") for (int ks = 0; ks < 2; ++ks)                       \
            af[mi][ks] = *reinterpret_cast<const bf16x8_t*>(rb + offA[qm][mi][ks]);
#define READ_B(qn)                                                             \
    _Pragma("unroll") for (int ni = 0; ni < 2; ++ni)                           \
        _Pragma("unroll") for (int ks = 0; ks < 2; ++ks)                       \
            bf[qn][ni][ks] = *reinterpret_cast<const bf16x8_t*>(rb + offB[qn][ni][ks]);

#define MFMA_QUAD(qm, qn)                                                      \
    __builtin_amdgcn_s_setprio(1);                                             \
    _Pragma("unroll") for (int mi = 0; mi < 4; ++mi)                           \
        _Pragma("unroll") for (int ni = 0; ni < 2; ++ni) {                     \
            acc[qm][qn][mi][ni] = __builtin_amdgcn_mfma_f32_16x16x32_bf16(     \
                af[mi][0], bf[qn][ni][0], acc[qm][qn][mi][ni], 0, 0, 0);       \
            acc[qm][qn][mi][ni] = __builtin_amdgcn_mfma_f32_16x16x32_bf16(     \
                af[mi][1], bf[qn][ni][1], acc[qm][qn][mi][ni], 0, 0, 0);       \
        }                                                                      \
    __builtin_amdgcn_s_setprio(0);

__device__ __forceinline__ void setup_256(
    const unsigned short* __restrict__ A, int lda,
    const unsigned short* __restrict__ B, int ldb,
    const unsigned short*& pA, const unsigned short*& pB,
    int offA[2][4][2], int offB[2][2][2]) {
    const int tid = threadIdx.x;
    const int wave = tid >> 6, lane = tid & 63;
    const int wsm = (wave >> 2) & 1, wsn = wave & 3;
    const int fr = lane & 15, g = lane >> 4;
    const int srow8 = lane >> 3;
    const int scolB = ((lane & 7) * 16) ^ (srow8 << 4);

    pA = A + (size_t)(wave * 16 + srow8) * lda + (scolB >> 1);
    pB = B + (size_t)(wave * 16 + srow8) * ldb + (scolB >> 1);

#pragma unroll
    for (int qm = 0; qm < 2; ++qm)
#pragma unroll
        for (int mi = 0; mi < 4; ++mi)
#pragma unroll
            for (int ks = 0; ks < 2; ++ks)
                offA[qm][mi][ks] = qm * 16384 + (wsm * 64 + mi * 16 + fr) * 128 +
                                   ((ks * 64 + g * 16) ^ ((fr & 7) << 4));
#pragma unroll
    for (int qn = 0; qn < 2; ++qn)
#pragma unroll
        for (int ni = 0; ni < 2; ++ni)
#pragma unroll
            for (int ks = 0; ks < 2; ++ks)
                offB[qn][ni][ks] = 32768 + qn * 16384 + (wsn * 32 + ni * 16 + fr) * 128 +
                                   ((ks * 64 + g * 16) ^ ((fr & 7) << 4));
}

// ===========================================================================
// ENGINE B (r8-verified): 2 phases x 32 MFMA per K-tile; vmcnt(2)/vmcnt(4)
// before their barrier; stage after barrier into buf^1. Used: vt, proj.
// ===========================================================================
template <bool LAST>
__device__ __forceinline__ void tile_step(
    const char* rb, char* wb, size_t kof,
    const unsigned short* pA, const unsigned short* pB, int lda, int ldb,
    int wave, const int offA[2][4][2], const int offB[2][2][2],
    f32x4_t acc[2][2][4][2]) {
    bf16x8_t af[4][2], bf[2][2][2];
    asm volatile("s_waitcnt vmcnt(2)" ::: "memory");
    asm volatile("s_barrier" ::: "memory");
    if constexpr (!LAST) { STA(0, 0); STA(0, 1); STB(0, 0); STB(0, 1); }
    READ_A(0); READ_B(0); READ_B(1);
    MFMA_QUAD(0, 0);
    MFMA_QUAD(0, 1);
    if constexpr (LAST) asm volatile("s_waitcnt vmcnt(0)" ::: "memory");
    else                asm volatile("s_waitcnt vmcnt(4)" ::: "memory");
    asm volatile("s_barrier" ::: "memory");
    if constexpr (!LAST) { STB(1, 0); STB(1, 1); STA(1, 0); STA(1, 1); }
    READ_A(1);
    MFMA_QUAD(1, 1);
    MFMA_QUAD(1, 0);
}

__device__ __forceinline__ void gemm_ml_256(
    const unsigned short* __restrict__ A, int lda,
    const unsigned short* __restrict__ B, int ldb,
    int K, char* smem, f32x4_t acc[2][2][4][2]) {
    const int wave = threadIdx.x >> 6;
    const unsigned short* pA;
    const unsigned short* pB;
    int offA[2][4][2], offB[2][2][2];
    setup_256(A, lda, B, ldb, pA, pB, offA, offB);

#pragma unroll
    for (int qm = 0; qm < 2; ++qm)
#pragma unroll
        for (int qn = 0; qn < 2; ++qn)
#pragma unroll
            for (int mi = 0; mi < 4; ++mi)
#pragma unroll
                for (int ni = 0; ni < 2; ++ni)
                    acc[qm][qn][mi][ni] = (f32x4_t){0.f, 0.f, 0.f, 0.f};

    const int NT = K >> 6;
    {
        char* wb = smem;
        const size_t kof = 0;
        STA(0, 0); STA(0, 1);
        STB(0, 0); STB(0, 1);
        STB(1, 0); STB(1, 1);
        STA(1, 0); STA(1, 1);
    }
    for (int t = 0; t < NT - 1; ++t) {
        const char* rb = smem + (size_t)(t & 1) * 65536;
        char* wb = smem + (size_t)((t & 1) ^ 1) * 65536;
        tile_step<false>(rb, wb, (size_t)(t + 1) * 64, pA, pB, lda, ldb,
                         wave, offA, offB, acc);
    }
    {
        const char* rb = smem + (size_t)((NT - 1) & 1) * 65536;
        tile_step<true>(rb, smem, 0, pA, pB, lda, ldb, wave, offA, offB, acc);
    }
}

// ===========================================================================
// ENGINE C (m201-faithful 8-phase): same geometry/swizzle as B, but per
// K-tile 4 phases x 16 MFMA with builtin barriers (no memory-clobber asm),
// per-phase 1-half stage, lgkmcnt(8) after the 12-read phase, lgkmcnt(0)+
// sched_barrier(0) after each pre-MFMA barrier (rule #18), vmcnt(6) ONLY at
// phases 4/8 (drains exactly the tile consumed next; 3 halves stay in
// flight). Stage slots (verified vs last-LDS-read, all >=1 barrier apart):
//   ph1: D1.A1<-t1 | ph2-5: D0.{A0,B0,B1,A1}<-t2 | ph6-8: D1.{A0,B0,B1}<-t3
// FIFO: entry 6 outstanding (t1.{A0,B0,B1}); ph4 vmcnt(6) drains t1 fully;
// ph8 vmcnt(6) drains t2 fully; invariant restored. Tail: ph1 stage only,
// ph4 vmcnt(0). Used: scores, pv (the two 86us kernels).
// ===========================================================================
#define SCA(d, h, kt) do {                                                     \
    char* db_ = smem + (d) * 65536 + (h) * 16384 + wave * 2048;                \
    __builtin_amdgcn_global_load_lds(                                          \
        (const AS1 void*)(pA + (kt) + (size_t)((h) * 128) * lda),              \
        (AS3 void*)db_, 16, 0, 0);                                             \
    __builtin_amdgcn_global_load_lds(                                          \
        (const AS1 void*)(pA + (kt) + (size_t)((h) * 128 + 8) * lda),          \
        (AS3 void*)(db_ + 1024), 16, 0, 0);                                    \
} while (0)
#define SCB(d, h, kt) do {                                                     \
    char* db_ = smem + (d) * 65536 + 32768 + (h) * 16384 + wave * 2048;        \
    __builtin_amdgcn_global_load_lds(                                          \
        (const AS1 void*)(pB + (kt) + (size_t)((h) * 128) * ldb),              \
        (AS3 void*)db_, 16, 0, 0);                                             \
    __builtin_amdgcn_global_load_lds(                                          \
        (const AS1 void*)(pB + (kt) + (size_t)((h) * 128 + 8) * ldb),          \
        (AS3 void*)(db_ + 1024), 16, 0, 0);                                    \
} while (0)

#define C_RA(d, qm)                                                            \
    _Pragma("unroll") for (int mi = 0; mi < 4; ++mi)                           \
    _Pragma("unroll") for (int ks = 0; ks < 2; ++ks)                           \
        af[mi][ks] = *reinterpret_cast<const bf16x8_t*>(                       \
            smem + (d) * 65536 + offA[qm][mi][ks]);
#define C_RB(d, qn, B_)                                                        \
    _Pragma("unroll") for (int ni = 0; ni < 2; ++ni)                           \
    _Pragma("unroll") for (int ks = 0; ks < 2; ++ks)                           \
        B_[ni][ks] = *reinterpret_cast<const bf16x8_t*>(                       \
            smem + (d) * 65536 + offB[qn][ni][ks]);

#define C_MQ(qm, qn, B_)                                                       \
    __builtin_amdgcn_s_setprio(1);                                             \
    _Pragma("unroll") for (int mi = 0; mi < 4; ++mi)                           \
    _Pragma("unroll") for (int ni = 0; ni < 2; ++ni) {                         \
        acc[qm][qn][mi][ni] = __builtin_amdgcn_mfma_f32_16x16x32_bf16(         \
            af[mi][0], B_[ni][0], acc[qm][qn][mi][ni], 0, 0, 0);               \
        acc[qm][qn][mi][ni] = __builtin_amdgcn_mfma_f32_16x16x32_bf16(         \
            af[mi][1], B_[ni][1], acc[qm][qn][mi][ni], 0, 0, 0);               \
    }                                                                          \
    __builtin_amdgcn_s_setprio(0);

#define C_BAR  __builtin_amdgcn_s_barrier()
#define C_LGK0 do { asm volatile("s_waitcnt lgkmcnt(0)");                      \
                    __builtin_amdgcn_sched_barrier(0); } while (0)

__device__ __forceinline__ void gemm_ml_256c(
    const unsigned short* __restrict__ A, int lda,
    const unsigned short* __restrict__ B, int ldb,
    int K, char* smem, f32x4_t acc[2][2][4][2]) {
    const int wave = threadIdx.x >> 6;
    const unsigned short* pA;
    const unsigned short* pB;
    int offA[2][4][2], offB[2][2][2];
    setup_256(A, lda, B, ldb, pA, pB, offA, offB);

#pragma unroll
    for (int qm = 0; qm < 2; ++qm)
#pragma unroll
        for (int qn = 0; qn < 2; ++qn)
#pragma unroll
            for (int mi = 0; mi < 4; ++mi)
#pragma unroll
                for (int ni = 0; ni < 2; ++ni)
                    acc[qm][qn][mi][ni] = (f32x4_t){0.f, 0.f, 0.f, 0.f};

    const int NT = K >> 6, NI = NT >> 1;   // K multiple of 128

    // prologue: t0 -> D0 {A0,B0,B1,A1}; t1 -> D1 {A0,B0,B1}
    SCA(0, 0, 0); SCB(0, 0, 0); SCB(0, 1, 0); SCA(0, 1, 0);
    SCA(1, 0, 64); SCB(1, 0, 64); SCB(1, 1, 64);
    asm volatile("s_waitcnt vmcnt(6)");     // t0 resident; t1 3 halves in flight
    C_BAR;

    size_t kk = 0;
    for (int it = 0; it < NI; ++it, kk += 128) {
        const bool L = (it == NI - 1);
        const size_t kt1 = kk + 64, kt2 = kk + 128, kt3 = kk + 192;
        bf16x8_t af[4][2], b0[2][2], b1[2][2];
        // ---- ph1: t0 q(0,0)  [12 ds_reads]
        C_RA(0, 0); C_RB(0, 0, b0);
        SCA(1, 1, kt1);
        asm volatile("s_waitcnt lgkmcnt(8)");
        C_BAR; C_LGK0;
        C_MQ(0, 0, b0);
        C_BAR;
        // ---- ph2: q(0,1)
        C_RB(0, 1, b1);
        if (!L) SCA(0, 0, kt2);
        C_BAR; C_LGK0;
        C_MQ(0, 1, b1);
        C_BAR;
        // ---- ph3: q(1,1)
        C_RA(0, 1);
        if (!L) SCB(0, 0, kt2);
        C_BAR; C_LGK0;
        C_MQ(1, 1, b1);
        C_BAR;
        // ---- ph4: q(1,0)  [vmcnt once per K-tile]
        if (!L) { SCB(0, 1, kt2); asm volatile("s_waitcnt vmcnt(6)"); }
        else    { asm volatile("s_waitcnt vmcnt(0)"); }
        C_BAR;
        C_MQ(1, 0, b0);
        C_BAR;
        // ---- ph5: t1 q(0,0)
        C_RA(1, 0); C_RB(1, 0, b0);
        if (!L) SCA(0, 1, kt2);
        asm volatile("s_waitcnt lgkmcnt(8)");
        C_BAR; C_LGK0;
        C_MQ(0, 0, b0);
        C_BAR;
        // ---- ph6: q(0,1)
        C_RB(1, 1, b1);
        if (!L) SCA(1, 0, kt3);
        C_BAR; C_LGK0;
        C_MQ(0, 1, b1);
        C_BAR;
        // ---- ph7: q(1,1)
        C_RA(1, 1);
        if (!L) SCB(1, 0, kt3);
        C_BAR; C_LGK0;
        C_MQ(1, 1, b1);
        C_BAR;
        // ---- ph8: q(1,0)
        if (!L) { SCB(1, 1, kt3); asm volatile("s_waitcnt vmcnt(6)"); }
        C_BAR;
        C_MQ(1, 0, b0);
        C_BAR;
    }
}

#define E256_IDX                                                \
    const int lane = threadIdx.x & 63, wave = threadIdx.x >> 6; \
    const int e_r0 = ((wave >> 2) & 1) * 64 + (lane >> 4) * 4;  \
    const int e_c0 = (wave & 3) * 32 + (lane & 15);

#define E256_LOOP(...)                                          \
    _Pragma("unroll") for (int qm = 0; qm < 2; ++qm)            \
    _Pragma("unroll") for (int qn = 0; qn < 2; ++qn)            \
    _Pragma("unroll") for (int mi = 0; mi < 4; ++mi)            \
    _Pragma("unroll") for (int ni = 0; ni < 2; ++ni)            \
    _Pragma("unroll") for (int j = 0; j < 4; ++j) { __VA_ARGS__ }

// Interleaved q/k layout: per batch z (8 total), base elem z*4194304:
//   q_z[2048][1024] at +0, k_z[2048][1024] at +2097152.
// Softmax output P_z[2048][2048] bf16 later overlays exactly this region.

// ---------------------------------------------------------------------------
// QKV GEMM, Q/K half (ENGINE A): M=16384, N=2048, K=1024
// ---------------------------------------------------------------------------
__global__ __launch_bounds__(512, 4) void k_gemm_qkv_qk(
    const unsigned short* __restrict__ x, const unsigned short* __restrict__ w,
    unsigned short* __restrict__ qk) {
    __shared__ __align__(16) char smem[73728];
    const size_t tm = (size_t)blockIdx.x * 256, tn = (size_t)blockIdx.y * 128;
    f32x4_t acc[4][4];
    gemm_ml_128(x + tm * 1024, 1024, w + tn * 1024, 1024, 1024, smem, acc);
    E128_IDX
    E128_LOOP(
        size_t m = tm + e_r0 + mi * 16 + j;
        size_t z = m >> 11;
        size_t nloc = m & 2047;
        int n = (int)tn + e_c0 + ni * 16;
        unsigned short v = f2b(acc[mi][ni][j]);
        size_t base = z * 4194304 + nloc * 1024;
        if (n < 1024) qk[base + n] = v;
        else          qk[base + 2097152 + (n - 1024)] = v;
    )
}

// ---------------------------------------------------------------------------
// QKV GEMM, V^T half (ENGINE B, operands swapped): M=1024, N=16384, K=1024
// ---------------------------------------------------------------------------
__global__ __launch_bounds__(512, 2) void k_gemm_vt(
    const unsigned short* __restrict__ wv, const unsigned short* __restrict__ x,
    unsigned short* __restrict__ vt) {
    __shared__ __align__(16) char smem[131072];
    const size_t tm = (size_t)blockIdx.x * 256, tn = (size_t)blockIdx.y * 256;
    f32x4_t acc[2][2][4][2];
    gemm_ml_256(wv + tm * 1024, 1024, x + tn * 1024, 1024, 1024, smem, acc);
    E256_IDX
    E256_LOOP(
        size_t m = tm + qm * 128 + e_r0 + mi * 16 + j;   // c
        size_t n = tn + qn * 128 + e_c0 + ni * 16;       // token
        vt[m * 16384 + n] = f2b(acc[qm][qn][mi][ni][j]);
    )
}

// ---------------------------------------------------------------------------
// Scores (ENGINE C): batch z = z0 + blockIdx.z; S = bf16((q·k)/32)
// ---------------------------------------------------------------------------
__global__ __launch_bounds__(512, 2) void k_gemm_scores(
    const unsigned short* __restrict__ qk, unsigned short* __restrict__ S, int z0) {
    __shared__ __align__(16) char smem[131072];
    const size_t z = z0 + blockIdx.z;
    const size_t tm = (size_t)blockIdx.x * 256, tn = (size_t)blockIdx.y * 256;
    const unsigned short* qz = qk + z * 4194304;
    const unsigned short* kz = qz + 2097152;
    f32x4_t acc[2][2][4][2];
    gemm_ml_256c(qz + tm * 1024, 1024, kz + tn * 1024, 1024, 1024, smem, acc);
    E256_IDX
    unsigned short* Sz = S + (size_t)blockIdx.z * 4194304;
    E256_LOOP(
        size_t m = tm + qm * 128 + e_r0 + mi * 16 + j;
        size_t n = tn + qn * 128 + e_c0 + ni * 16;
        Sz[m * 2048 + n] = f2b(acc[qm][qn][mi][ni][j] * 0.03125f);
    )
}

// ---------------------------------------------------------------------------
// Row softmax: NZ*2048 rows x 2048, bf16 in -> bf16 out (P overlays q/k)
// ---------------------------------------------------------------------------
__global__ __launch_bounds__(256) void k_softmax(const unsigned short* __restrict__ S,
                                                 unsigned short* __restrict__ qk,
                                                 int z0) {
    const size_t r = blockIdx.x;
    const int t = threadIdx.x, wv = t >> 6, ln = t & 63;
    const uint4 u = reinterpret_cast<const uint4*>(S + r * 2048)[t];
    float vals[8];
    vals[0] = b2f((unsigned short)(u.x & 0xffff)); vals[1] = b2f((unsigned short)(u.x >> 16));
    vals[2] = b2f((unsigned short)(u.y & 0xffff)); vals[3] = b2f((unsigned short)(u.y >> 16));
    vals[4] = b2f((unsigned short)(u.z & 0xffff)); vals[5] = b2f((unsigned short)(u.z >> 16));
    vals[6] = b2f((unsigned short)(u.w & 0xffff)); vals[7] = b2f((unsigned short)(u.w >> 16));

    float mx = vals[0];
#pragma unroll
    for (int i = 1; i < 8; ++i) mx = fmaxf(mx, vals[i]);
#pragma unroll
    for (int i = 32; i > 0; i >>= 1) mx = fmaxf(mx, __shfl_xor(mx, i, 64));
    __shared__ float red[8];
    if (ln == 0) red[wv] = mx;
    __syncthreads();
    mx = fmaxf(fmaxf(red[0], red[1]), fmaxf(red[2], red[3]));

    float ex[8], s = 0.f;
#pragma unroll
    for (int i = 0; i < 8; ++i) { ex[i] = __expf(vals[i] - mx); s += ex[i]; }
#pragma unroll
    for (int i = 32; i > 0; i >>= 1) s += __shfl_xor(s, i, 64);
    if (ln == 0) red[4 + wv] = s;
    __syncthreads();
    s = (red[4] + red[5]) + (red[6] + red[7]);
    float inv = 1.0f / s;

    uint4 o;
    o.x = (unsigned)f2b(ex[0] * inv) | ((unsigned)f2b(ex[1] * inv) << 16);
    o.y = (unsigned)f2b(ex[2] * inv) | ((unsigned)f2b(ex[3] * inv) << 16);
    o.z = (unsigned)f2b(ex[4] * inv) | ((unsigned)f2b(ex[5] * inv) << 16);
    o.w = (unsigned)f2b(ex[6] * inv) | ((unsigned)f2b(ex[7] * inv) << 16);

    const size_t zg = z0 + (r >> 11), nloc = r & 2047;
    reinterpret_cast<uint4*>(qk + zg * 4194304 + nloc * 2048)[t] = o;
}

// ---------------------------------------------------------------------------
// PV as O^T (ENGINE C): O^T[c][n] = sum_m vt[c][m] * P[n][m]
// M=1024 (c), N=2048 (n), K=2048; scrambled coalesced stores.
// ---------------------------------------------------------------------------
__global__ __launch_bounds__(512, 2) void k_gemm_pv(
    const unsigned short* __restrict__ vt, const unsigned short* __restrict__ qk,
    unsigned short* __restrict__ ob, int z0) {
    __shared__ __align__(16) char smem[131072];
    const size_t z = z0 + blockIdx.z;
    const size_t tm = (size_t)blockIdx.x * 256, tn = (size_t)blockIdx.y * 256;
    const unsigned short* P = qk + z * 4194304;
    f32x4_t acc[2][2][4][2];
    gemm_ml_256c(vt + tm * 16384 + z * 2048, 16384,
                 P + tn * 2048, 2048, 2048, smem, acc);
    E256_IDX
    unsigned short* oz = ob + z * 2097152;
    E256_LOOP(
        size_t m = tm + qm * 128 + e_r0 + mi * 16 + j;   // c
        size_t n = tn + qn * 128 + e_c0 + ni * 16;       // token n within batch
        oz[(2 * m + (n >> 10)) * 1024 + (n & 1023)] = f2b(acc[qm][qn][mi][ni][j]);
    )
}

// ---------------------------------------------------------------------------
// Proj (ENGINE B): out[m][d] = sum_j o2[m][j] * w_proj[d][j] + b_proj[d]
// ---------------------------------------------------------------------------
__global__ __launch_bounds__(512, 2) void k_gemm_proj(
    const unsigned short* __restrict__ o2, const unsigned short* __restrict__ w,
    const float* __restrict__ bias, float* __restrict__ out) {
    __shared__ __align__(16) char smem[131072];
    const size_t tm = (size_t)blockIdx.x * 256, tn = (size_t)blockIdx.y * 256;
    f32x4_t acc[2][2][4][2];
    gemm_ml_256(o2 + tm * 1024, 1024, w + tn * 1024, 1024, 1024, smem, acc);
    E256_IDX
    E256_LOOP(
        size_t m = tm + qm * 128 + e_r0 + mi * 16 + j;
        size_t n = tn + qn * 128 + e_c0 + ni * 16;
        out[m * 1024 + n] = acc[qm][qn][mi][ni][j] + bias[n];
    )
}

// ---------------------------------------------------------------------------
extern "C" void kernel_launch(void* const* d_in, const int* in_sizes, int n_in,
                              void* d_out, int out_size, void* d_ws, size_t ws_size,
                              hipStream_t stream) {
    const float* x     = (const float*)d_in[0];
    const float* wqkv  = (const float*)d_in[1];
    const float* wproj = (const float*)d_in[2];
    const float* bproj = (const float*)d_in[3];
    float* out = (float*)d_out;
    char* ws = (char*)d_ws;

    // workspace layout (bytes):
    const size_t off_xb    = 0;             // 33,554,432 x bf16 (obuf overlays)
    const size_t off_wqkv  = 33554432;      //  6,291,456
    const size_t off_wproj = 39845888;      //  2,097,152
    const size_t off_qk    = 41943040;      // 67,108,864 interleaved q/k (P overlays)
    const size_t off_vt    = 109051904;     // 33,554,432
    const size_t off_S     = 142606336;     // NZ * 8,388,608 bf16 logits chunk
    int NZ = 0;
    for (int c = 8; c >= 1; c >>= 1)
        if (off_S + (size_t)c * 8388608 <= ws_size) { NZ = c; break; }
    if (NZ == 0) return;  // fail loudly via absmax check

    unsigned short* xb     = (unsigned short*)(ws + off_xb);
    unsigned short* wqkvb  = (unsigned short*)(ws + off_wqkv);
    unsigned short* wprojb = (unsigned short*)(ws + off_wproj);
    unsigned short* qkb    = (unsigned short*)(ws + off_qk);
    unsigned short* vtb    = (unsigned short*)(ws + off_vt);
    unsigned short* Sb     = (unsigned short*)(ws + off_S);
    unsigned short* obuf   = (unsigned short*)(ws + off_xb);  // overlay

    k_f2b<<<16384, 256, 0, stream>>>(x, xb, 4194304);
    k_f2b<<<3072, 256, 0, stream>>>(wqkv, wqkvb, 786432);
    k_f2b<<<1024, 256, 0, stream>>>(wproj, wprojb, 262144);

    k_gemm_qkv_qk<<<dim3(64, 16), 512, 0, stream>>>(xb, wqkvb, qkb);
    k_gemm_vt<<<dim3(4, 64), 512, 0, stream>>>(wqkvb + (size_t)2048 * 1024, xb, vtb);

    for (int z0 = 0; z0 < 8; z0 += NZ) {
        k_gemm_scores<<<dim3(8, 8, NZ), 512, 0, stream>>>(qkb, Sb, z0);
        k_softmax<<<NZ * 2048, 256, 0, stream>>>(Sb, qkb, z0);
        k_gemm_pv<<<dim3(4, 8, NZ), 512, 0, stream>>>(vtb, qkb, obuf, z0);
    }
    k_gemm_proj<<<dim3(64, 4), 512, 0, stream>>>(obuf, wprojb, bproj, out);
}